// Round 1
// baseline (123.239 us; speedup 1.0000x reference)
//
#include <hip/hip_runtime.h>
#include <cmath>

#define NWALK 4096
#define NXD   48
#define HID   256
#define WPB   8
#define GCONST 0.7978845608028654f

typedef _Float16 half8   __attribute__((ext_vector_type(8)));
typedef float    float4v __attribute__((ext_vector_type(4)));

// ---------- prep_all: blocks 0..15: W2 transpose->fp16 + W1 cast; blocks 16..271: layer-1
// (unchanged, verified)
__global__ __launch_bounds__(256) void prep_all(const float* __restrict__ W2,
                                                const float* __restrict__ W1,
                                                const float* __restrict__ x,
                                                const float* __restrict__ b1,
                                                _Float16* __restrict__ W2c,
                                                _Float16* __restrict__ W1c,
                                                _Float16* __restrict__ t1h,
                                                _Float16* __restrict__ h1h,
                                                _Float16* __restrict__ ch) {
    __shared__ float tile[64][65];
    __shared__ float xs[16][NXD];

    if (blockIdx.x < 16) {
        const int bi = blockIdx.x & 3;
        const int bj = blockIdx.x >> 2;
        const int tx = threadIdx.x & 63;
        const int ty = threadIdx.x >> 6;
        #pragma unroll
        for (int r = 0; r < 16; ++r) {
            int il = ty * 16 + r;
            tile[tx][il] = W2[(bi * 64 + il) * HID + bj * 64 + tx];
        }
        __syncthreads();
        #pragma unroll
        for (int r = 0; r < 16; ++r) {
            int jl = ty * 16 + r;
            W2c[(bj * 64 + jl) * HID + bi * 64 + tx] = (_Float16)tile[jl][tx];
        }
        #pragma unroll
        for (int r = 0; r < 3; ++r) {
            int k = blockIdx.x * 3 + r;
            W1c[k * HID + threadIdx.x] = (_Float16)W1[k * HID + threadIdx.x];
        }
    } else {
        const int i  = threadIdx.x;
        const int w0 = (blockIdx.x - 16) * 16;

        float col[NXD];
        float S = 0.f;
        #pragma unroll
        for (int k = 0; k < NXD; ++k) {
            float v = W1[k * HID + i];
            col[k] = v;
            S = fmaf(v, v, S);
        }
        #pragma unroll
        for (int t = threadIdx.x; t < 16 * NXD; t += 256)
            ((float*)xs)[t] = x[w0 * NXD + t];
        __syncthreads();

        const float b = b1[i];
        #pragma unroll 4
        for (int w = 0; w < 16; ++w) {
            float a1 = b;
            #pragma unroll
            for (int k = 0; k < NXD; ++k)
                a1 = fmaf(xs[w][k], col[k], a1);
            float h1 = tanhf(a1);
            float t1 = 1.f - h1 * h1;
            int off = (w0 + w) * HID + i;
            t1h[off] = (_Float16)t1;
            h1h[off] = (_Float16)h1;
            ch[off]  = (_Float16)(S * h1 * t1);
        }
    }
}

// ---------- prep2: batched a2/p GEMM + activation precompute ----------
// a2 = W2^T h1, p = W2^T c  (identical MFMA chaining as the old kt=3 pass),
// then u = w3*(1-h2^2), uh2 = u*h2 (fp32), rt2 = sum(u*p) per walker.
__global__ __launch_bounds__(256) void prep2(
    const float* __restrict__ b2, const float* __restrict__ w3,
    const _Float16* __restrict__ W2c,
    const _Float16* __restrict__ h1h, const _Float16* __restrict__ ch,
    float* __restrict__ uf, float* __restrict__ uhf, float* __restrict__ rt2g)
{
    __shared__ float b2s[HID], w3s[HID];
    __shared__ float r2s[4][8];

    const int tid  = threadIdx.x;
    const int wave = tid >> 6;
    const int lane = tid & 63;
    const int n16  = lane & 15;
    const int quad = lane >> 4;
    const int w0   = blockIdx.x * 8;

    b2s[tid] = b2[tid];
    w3s[tid] = w3[tid];

    // A fragments: W2c rows i (same layout as eloc8)
    half8 afr[8][4];
    #pragma unroll
    for (int s = 0; s < 8; ++s)
        #pragma unroll
        for (int a = 0; a < 4; ++a)
            afr[s][a] = *(const half8*)(W2c + ((wave * 4 + a) * 16 + n16) * HID
                                        + s * 32 + quad * 8);

    // B column n16 -> walker n16>>1, even = h1 row, odd = c row (read direct from global)
    const _Float16* src  = (n16 & 1) ? ch : h1h;
    const _Float16* brow = src + (size_t)(w0 + (n16 >> 1)) * HID;

    float4v acc[4];
    #pragma unroll
    for (int a = 0; a < 4; ++a) acc[a] = (float4v){0.f, 0.f, 0.f, 0.f};
    #pragma unroll
    for (int s = 0; s < 8; ++s) {
        half8 bf = *(const half8*)(brow + (s * 4 + quad) * 8);
        #pragma unroll
        for (int a = 0; a < 4; ++a)
            acc[a] = __builtin_amdgcn_mfma_f32_16x16x32_f16(afr[s][a], bf, acc[a], 0, 0, 0);
    }

    __syncthreads();   // b2s/w3s ready

    const int w = n16 >> 1;
    float um[4][4];
    #pragma unroll
    for (int a = 0; a < 4; ++a)
        #pragma unroll
        for (int reg = 0; reg < 4; ++reg) um[a][reg] = 0.f;

    if (!(n16 & 1)) {  // even columns hold a2
        #pragma unroll
        for (int a = 0; a < 4; ++a)
            #pragma unroll
            for (int reg = 0; reg < 4; ++reg) {
                int i   = (wave * 4 + a) * 16 + quad * 4 + reg;
                float a2 = acc[a][reg] + b2s[i];
                float h2 = tanhf(a2);
                float t2 = 1.f - h2 * h2;
                float u  = w3s[i] * t2;
                um[a][reg] = u;
                uf [(size_t)(w0 + w) * HID + i] = u;
                uhf[(size_t)(w0 + w) * HID + i] = u * h2;
            }
    }

    // rt2 = sum_i u_i * p_i : odd columns hold p; pull u from even neighbor
    float part = 0.f;
    #pragma unroll
    for (int a = 0; a < 4; ++a)
        #pragma unroll
        for (int reg = 0; reg < 4; ++reg) {
            float uo = __shfl_xor(um[a][reg], 1, 64);
            part = fmaf(uo, acc[a][reg], part);
        }
    part += __shfl_xor(part, 16, 64);
    part += __shfl_xor(part, 32, 64);
    if (quad == 0 && (n16 & 1)) r2s[wave][w] = part;
    __syncthreads();
    if (tid < 8)
        rt2g[w0 + tid] = r2s[0][tid] + r2s[1][tid] + r2s[2][tid] + r2s[3][tid];
}

// ---------- eloc8: 3 MFMA passes/walker, no activation chain, deferred combine
__global__ __launch_bounds__(256, 2) void eloc8(
    const float* __restrict__ x,
    const _Float16* __restrict__ W2c,
    const _Float16* __restrict__ W1c,
    const _Float16* __restrict__ t1h,
    const float* __restrict__ uf,
    const float* __restrict__ uhf,
    const float* __restrict__ rt2g,
    float* __restrict__ out)
{
    __shared__ __align__(16) _Float16 AsT[2][48 * HID];   // 48 KiB, walker-parity
    __shared__ float xs[WPB][NXD];                        // 1536 B
    __shared__ float gw[WPB][4][NXD];                     // 6144 B (per-walker, kept to end)
    __shared__ float rt1p[WPB][4][16];                    // 2048 B (quad-reduced partials)

    const int w0   = blockIdx.x * WPB;
    const int tid  = threadIdx.x;
    const int wave = tid >> 6;
    const int lane = tid & 63;
    const int n16  = lane & 15;
    const int quad = (tid >> 4) & 3;
    const int ci   = tid & 31;     // staging i-chunk
    const int k0   = tid >> 5;     // staging k-row base

    // ---- full A-residency: 8 steps x 4 j-tiles = 128 regs, loaded ONCE ----
    half8 afr[8][4];
    #pragma unroll
    for (int s = 0; s < 8; ++s)
        #pragma unroll
        for (int a = 0; a < 4; ++a)
            afr[s][a] = *(const half8*)(W2c + ((wave * 4 + a) * 16 + n16) * HID
                                        + s * 32 + quad * 8);

    // ---- W1c staging operand is walker-invariant: hold in 6 half8 regs ----
    half8 w1r[6];
    #pragma unroll
    for (int s2 = 0; s2 < 6; ++s2)
        w1r[s2] = *(const half8*)(W1c + (s2 * 8 + k0) * HID + ci * 8);

    #pragma unroll
    for (int t = tid; t < WPB * NXD; t += 256)
        ((float*)xs)[t] = x[w0 * NXD + t];

    // stage walker 0 into buffer 0
    {
        half8 th = *(const half8*)(t1h + (size_t)w0 * HID + ci * 8);
        #pragma unroll
        for (int s2 = 0; s2 < 6; ++s2) {
            int k = s2 * 8 + k0;
            *(half8*)(AsT[0] + k * HID + ((ci ^ (k & 7)) * 8)) = w1r[s2] * th;
        }
    }
    __syncthreads();

    #pragma unroll 1
    for (int ww = 0; ww < WPB; ++ww) {
        const int cur = ww & 1, nxt = cur ^ 1;
        const int wg  = w0 + ww;
        const _Float16* curA = AsT[cur];
        const bool more = (ww + 1 < WPB);

        // T14 split: issue next-walker t1 load NOW (unconditional addr so it isn't sunk),
        // consume in ds_writes after the MFMA passes.
        const int wn = more ? (wg + 1) : wg;
        half8 th = *(const half8*)(t1h + (size_t)wn * HID + ci * 8);

        // per-walker u / uh2 fold operands (8 broadcast float4 loads -> 32 regs)
        const float* ub = uf  + (size_t)wg * HID + wave * 64 + quad * 4;
        const float* hb = uhf + (size_t)wg * HID + wave * 64 + quad * 4;
        float4v uu[4], uh[4];
        #pragma unroll
        for (int a = 0; a < 4; ++a) uu[a] = *(const float4v*)(ub + a * 16);
        #pragma unroll
        for (int a = 0; a < 4; ++a) uh[a] = *(const float4v*)(hb + a * 16);

        float rt1 = 0.f;
        #pragma unroll 1
        for (int kt = 0; kt < 3; ++kt) {
            float4v acc[4];
            #pragma unroll
            for (int a = 0; a < 4; ++a) acc[a] = (float4v){0.f, 0.f, 0.f, 0.f};
            const int krow = kt * 16 + n16;
            __builtin_amdgcn_s_setprio(1);
            #pragma unroll
            for (int s = 0; s < 8; ++s) {
                half8 bf = *(const half8*)(curA + krow * HID
                            + ((((s * 4 + quad) ^ (krow & 7)) << 3)));
                #pragma unroll
                for (int a = 0; a < 4; ++a)
                    acc[a] = __builtin_amdgcn_mfma_f32_16x16x32_f16(
                        afr[s][a], bf, acc[a], 0, 0, 0);
            }
            __builtin_amdgcn_s_setprio(0);
            float g = 0.f;
            #pragma unroll
            for (int a = 0; a < 4; ++a)
                #pragma unroll
                for (int reg = 0; reg < 4; ++reg) {
                    float m = acc[a][reg];
                    rt1 = fmaf(m * m, uh[a][reg], rt1);
                    g   = fmaf(m, uu[a][reg], g);
                }
            // shallow 2-level quad reduce (keeps g scalar; no runtime-indexed array)
            g += __shfl_xor(g, 16, 64);
            g += __shfl_xor(g, 32, 64);
            if (lane < 16) gw[ww][wave][kt * 16 + lane] = g;
        }

        rt1 += __shfl_xor(rt1, 16, 64);
        rt1 += __shfl_xor(rt1, 32, 64);
        if (lane < 16) rt1p[ww][wave][lane] = rt1;

        // stage next walker into other buffer (loads already in flight)
        if (more) {
            #pragma unroll
            for (int s2 = 0; s2 < 6; ++s2) {
                int k = s2 * 8 + k0;
                *(half8*)(AsT[nxt] + k * HID + ((ci ^ (k & 7)) * 8)) = w1r[s2] * th;
            }
        }
        __syncthreads();   // AsT[nxt] ready; rt1p/gw[ww] durable (never overwritten)
    }

    // ---- deferred final combine: wave handles walkers 2*wave, 2*wave+1 ----
    const int wa = 2 * wave, wb = wa + 1;
    float rt2a = rt2g[w0 + wa];
    float rt2b = rt2g[w0 + wb];

    float r0 = rt1p[wa][quad][n16];
    float r1 = rt1p[wb][quad][n16];

    float ga = 0.f, gb = 0.f, xa = 0.f, xb = 0.f;
    if (lane < NXD) {
        ga = gw[wa][0][lane] + gw[wa][1][lane] + gw[wa][2][lane] + gw[wa][3][lane];
        gb = gw[wb][0][lane] + gw[wb][1][lane] + gw[wb][2][lane] + gw[wb][3][lane];
        xa = xs[wa][lane];
        xb = xs[wb][lane];
    }
    float gga = ga * ga, ggb = gb * gb;
    float pa = 0.5f * xa * xa, pb = 0.5f * xb * xb;
    #pragma unroll
    for (int off = 32; off > 0; off >>= 1) {
        r0  += __shfl_down(r0,  off, 64);
        r1  += __shfl_down(r1,  off, 64);
        gga += __shfl_down(gga, off, 64);
        ggb += __shfl_down(ggb, off, 64);
        pa  += __shfl_down(pa,  off, 64);
        pb  += __shfl_down(pb,  off, 64);
    }
    if (lane == 0) {
        float kina = r0 + rt2a - 0.5f * gga;
        float kinb = r1 + rt2b - 0.5f * ggb;

        float x0 = xs[wa][0], x1 = xs[wa][1], x2 = xs[wa][2];
        float x3 = xs[wa][3], x4 = xs[wa][4], x5 = xs[wa][5];
        float d01 = (x0-x1)*(x0-x1) + (x2-x1)*(x2-x1);
        float d02 = (x0-x2)*(x0-x2) + (x1-x2)*(x1-x2);
        float d12 = (x3-x5)*(x3-x5) + (x4-x5)*(x4-x5);
        float intera = GCONST * (expf(-2.f*d01) + expf(-2.f*d02) + expf(-2.f*d12));

        x0 = xs[wb][0]; x1 = xs[wb][1]; x2 = xs[wb][2];
        x3 = xs[wb][3]; x4 = xs[wb][4]; x5 = xs[wb][5];
        float e01 = (x0-x1)*(x0-x1) + (x2-x1)*(x2-x1);
        float e02 = (x0-x2)*(x0-x2) + (x1-x2)*(x1-x2);
        float e12 = (x3-x5)*(x3-x5) + (x4-x5)*(x4-x5);
        float interb = GCONST * (expf(-2.f*e01) + expf(-2.f*e02) + expf(-2.f*e12));

        const int wga = w0 + wa, wgb = w0 + wb;
        out[wga]             = kina + pa + intera;
        out[NWALK + wga]     = kina;
        out[2 * NWALK + wga] = pa;
        out[3 * NWALK + wga] = intera;
        out[wgb]             = kinb + pb + interb;
        out[NWALK + wgb]     = kinb;
        out[2 * NWALK + wgb] = pb;
        out[3 * NWALK + wgb] = interb;
    }
}

extern "C" void kernel_launch(void* const* d_in, const int* in_sizes, int n_in,
                              void* d_out, int out_size, void* d_ws, size_t ws_size,
                              hipStream_t stream) {
    const float* x  = (const float*)d_in[0];
    const float* W1 = (const float*)d_in[1];
    const float* b1 = (const float*)d_in[2];
    const float* W2 = (const float*)d_in[3];
    const float* b2 = (const float*)d_in[4];
    const float* w3 = (const float*)d_in[5];
    float* out = (float*)d_out;

    char* ws = (char*)d_ws;
    _Float16* W2c = (_Float16*)(ws);                       // 128 KB
    _Float16* W1c = (_Float16*)(ws + 131072);              // 24 KB
    _Float16* t1h = (_Float16*)(ws + 155648);              // 2 MB
    _Float16* h1h = (_Float16*)(ws + 2252800);             // 2 MB
    _Float16* chv = (_Float16*)(ws + 4349952);             // 2 MB
    float*    uf  = (float*)(ws + 6447104);                // 4 MB
    float*    uhf = (float*)(ws + 10641408);               // 4 MB
    float*    r2g = (float*)(ws + 14835712);               // 16 KB

    prep_all<<<16 + NWALK / 16, 256, 0, stream>>>(W2, W1, x, b1, W2c, W1c, t1h, h1h, chv);
    prep2<<<NWALK / 8, 256, 0, stream>>>(b2, w3, W2c, h1h, chv, uf, uhf, r2g);
    eloc8<<<NWALK / WPB, 256, 0, stream>>>(x, W2c, W1c, t1h, uf, uhf, r2g, out);
}

// Round 2
// 109.067 us; speedup vs baseline: 1.1299x; 1.1299x over previous
//
#include <hip/hip_runtime.h>
#include <cmath>

#define NWALK 4096
#define NXD   48
#define HID   256
#define WPB   8
#define GCONST 0.7978845608028654f

typedef _Float16 half8   __attribute__((ext_vector_type(8)));
typedef float    float4v __attribute__((ext_vector_type(4)));

// ---------- prep_all: blocks 0..15: W2 transpose->fp16 + W1 cast; blocks 16..271: layer-1
// (unchanged, verified)
__global__ __launch_bounds__(256) void prep_all(const float* __restrict__ W2,
                                                const float* __restrict__ W1,
                                                const float* __restrict__ x,
                                                const float* __restrict__ b1,
                                                _Float16* __restrict__ W2c,
                                                _Float16* __restrict__ W1c,
                                                _Float16* __restrict__ t1h,
                                                _Float16* __restrict__ h1h,
                                                _Float16* __restrict__ ch) {
    __shared__ float tile[64][65];
    __shared__ float xs[16][NXD];

    if (blockIdx.x < 16) {
        const int bi = blockIdx.x & 3;
        const int bj = blockIdx.x >> 2;
        const int tx = threadIdx.x & 63;
        const int ty = threadIdx.x >> 6;
        #pragma unroll
        for (int r = 0; r < 16; ++r) {
            int il = ty * 16 + r;
            tile[tx][il] = W2[(bi * 64 + il) * HID + bj * 64 + tx];
        }
        __syncthreads();
        #pragma unroll
        for (int r = 0; r < 16; ++r) {
            int jl = ty * 16 + r;
            W2c[(bj * 64 + jl) * HID + bi * 64 + tx] = (_Float16)tile[jl][tx];
        }
        #pragma unroll
        for (int r = 0; r < 3; ++r) {
            int k = blockIdx.x * 3 + r;
            W1c[k * HID + threadIdx.x] = (_Float16)W1[k * HID + threadIdx.x];
        }
    } else {
        const int i  = threadIdx.x;
        const int w0 = (blockIdx.x - 16) * 16;

        float col[NXD];
        float S = 0.f;
        #pragma unroll
        for (int k = 0; k < NXD; ++k) {
            float v = W1[k * HID + i];
            col[k] = v;
            S = fmaf(v, v, S);
        }
        #pragma unroll
        for (int t = threadIdx.x; t < 16 * NXD; t += 256)
            ((float*)xs)[t] = x[w0 * NXD + t];
        __syncthreads();

        const float b = b1[i];
        #pragma unroll 4
        for (int w = 0; w < 16; ++w) {
            float a1 = b;
            #pragma unroll
            for (int k = 0; k < NXD; ++k)
                a1 = fmaf(xs[w][k], col[k], a1);
            float h1 = tanhf(a1);
            float t1 = 1.f - h1 * h1;
            int off = (w0 + w) * HID + i;
            t1h[off] = (_Float16)t1;
            h1h[off] = (_Float16)h1;
            ch[off]  = (_Float16)(S * h1 * t1);
        }
    }
}

// ---------- eloc8: prep2 folded into prologue; single-buffered AsT; deferred combine
__global__ __launch_bounds__(256, 2) void eloc8(
    const float* __restrict__ x,
    const float* __restrict__ b2,
    const float* __restrict__ w3,
    const _Float16* __restrict__ W2c,
    const _Float16* __restrict__ W1c,
    const _Float16* __restrict__ t1h,
    const _Float16* __restrict__ h1h,
    const _Float16* __restrict__ ch,
    float* __restrict__ out)
{
    __shared__ __align__(16) _Float16 AsT[48 * HID];      // 24 KiB, single buffer
    __shared__ float xs[WPB][NXD];                        // 1536 B
    __shared__ float gw[WPB][4][NXD];                     // 6144 B (per-walker, kept to end)
    __shared__ float rt1p[WPB][4][16];                    // 2048 B
    __shared__ float us[WPB][HID], uhs[WPB][HID];         // 16 KiB fp32 (prep2 outputs)
    __shared__ float b2s[HID], w3s[HID];                  // 2 KiB
    __shared__ float r2s[4][WPB];                         // 128 B
    __shared__ float rt2s[WPB];                           // 32 B

    const int w0   = blockIdx.x * WPB;
    const int tid  = threadIdx.x;
    const int wave = tid >> 6;
    const int lane = tid & 63;
    const int n16  = lane & 15;
    const int quad = (tid >> 4) & 3;
    const int ci   = tid & 31;     // staging i-chunk
    const int k0   = tid >> 5;     // staging k-row base

    // ---- full A-residency: 8 steps x 4 j-tiles = 128 regs, loaded ONCE ----
    half8 afr[8][4];
    #pragma unroll
    for (int s = 0; s < 8; ++s)
        #pragma unroll
        for (int a = 0; a < 4; ++a)
            afr[s][a] = *(const half8*)(W2c + ((wave * 4 + a) * 16 + n16) * HID
                                        + s * 32 + quad * 8);

    // ---- W1c staging operand is walker-invariant: hold in 6 half8 regs ----
    half8 w1r[6];
    #pragma unroll
    for (int s2 = 0; s2 < 6; ++s2)
        w1r[s2] = *(const half8*)(W1c + (s2 * 8 + k0) * HID + ci * 8);

    b2s[tid] = b2[tid];
    w3s[tid] = w3[tid];
    #pragma unroll
    for (int t = tid; t < WPB * NXD; t += 256)
        ((float*)xs)[t] = x[w0 * NXD + t];

    // ---- prologue GEMM (old prep2): a2 = W2^T h1 (even cols), p = W2^T c (odd cols)
    // B column n16 -> walker n16>>1; even = h1 row, odd = c row (global reads)
    {
        const _Float16* src  = (n16 & 1) ? ch : h1h;
        const _Float16* brow = src + (size_t)(w0 + (n16 >> 1)) * HID;

        float4v acc[4];
        #pragma unroll
        for (int a = 0; a < 4; ++a) acc[a] = (float4v){0.f, 0.f, 0.f, 0.f};
        #pragma unroll
        for (int s = 0; s < 8; ++s) {
            half8 bf = *(const half8*)(brow + (s * 4 + quad) * 8);
            #pragma unroll
            for (int a = 0; a < 4; ++a)
                acc[a] = __builtin_amdgcn_mfma_f32_16x16x32_f16(afr[s][a], bf, acc[a], 0, 0, 0);
        }

        // stage walker 0 into AsT while acc settles
        half8 th0 = *(const half8*)(t1h + (size_t)w0 * HID + ci * 8);
        #pragma unroll
        for (int s2 = 0; s2 < 6; ++s2) {
            int k = s2 * 8 + k0;
            *(half8*)(AsT + k * HID + ((ci ^ (k & 7)) * 8)) = w1r[s2] * th0;
        }

        __syncthreads();   // b2s/w3s visible

        const int w = n16 >> 1;
        float um[4][4];
        #pragma unroll
        for (int a = 0; a < 4; ++a)
            #pragma unroll
            for (int reg = 0; reg < 4; ++reg) um[a][reg] = 0.f;

        if (!(n16 & 1)) {  // even columns hold a2 -> activation, u/uh2 to LDS
            #pragma unroll
            for (int a = 0; a < 4; ++a)
                #pragma unroll
                for (int reg = 0; reg < 4; ++reg) {
                    int i    = (wave * 4 + a) * 16 + quad * 4 + reg;
                    float a2 = acc[a][reg] + b2s[i];
                    float h2 = tanhf(a2);
                    float t2 = 1.f - h2 * h2;
                    float u  = w3s[i] * t2;
                    um[a][reg] = u;
                    us [w][i] = u;
                    uhs[w][i] = u * h2;
                }
        }

        // rt2 = sum_i u_i * p_i : odd columns hold p; pull u from even neighbor
        float part = 0.f;
        #pragma unroll
        for (int a = 0; a < 4; ++a)
            #pragma unroll
            for (int reg = 0; reg < 4; ++reg) {
                float uo = __shfl_xor(um[a][reg], 1, 64);
                part = fmaf(uo, acc[a][reg], part);
            }
        part += __shfl_xor(part, 16, 64);
        part += __shfl_xor(part, 32, 64);
        if (quad == 0 && (n16 & 1)) r2s[wave][w] = part;
    }
    __syncthreads();
    if (tid < WPB)
        rt2s[tid] = r2s[0][tid] + r2s[1][tid] + r2s[2][tid] + r2s[3][tid];
    __syncthreads();   // AsT walker-0, us/uhs, rt2s all ready

    #pragma unroll 1
    for (int ww = 0; ww < WPB; ++ww) {
        const int wg   = w0 + ww;
        const bool more = (ww + 1 < WPB);

        // T14 split: issue next-walker t1 load NOW, consume in ds_writes after passes
        const int wn = more ? (wg + 1) : wg;
        half8 th = *(const half8*)(t1h + (size_t)wn * HID + ci * 8);

        // per-walker u / uh2 fold operands: quad-broadcast ds_read_b128 (32 regs)
        float4v uu[4], uh[4];
        #pragma unroll
        for (int a = 0; a < 4; ++a)
            uu[a] = *(const float4v*)(&us[ww][(wave * 4 + a) * 16 + quad * 4]);
        #pragma unroll
        for (int a = 0; a < 4; ++a)
            uh[a] = *(const float4v*)(&uhs[ww][(wave * 4 + a) * 16 + quad * 4]);

        float rt1 = 0.f;
        #pragma unroll 1
        for (int kt = 0; kt < 3; ++kt) {
            float4v acc[4];
            #pragma unroll
            for (int a = 0; a < 4; ++a) acc[a] = (float4v){0.f, 0.f, 0.f, 0.f};
            const int krow = kt * 16 + n16;
            __builtin_amdgcn_s_setprio(1);
            #pragma unroll
            for (int s = 0; s < 8; ++s) {
                half8 bf = *(const half8*)(AsT + krow * HID
                            + ((((s * 4 + quad) ^ (krow & 7)) << 3)));
                #pragma unroll
                for (int a = 0; a < 4; ++a)
                    acc[a] = __builtin_amdgcn_mfma_f32_16x16x32_f16(
                        afr[s][a], bf, acc[a], 0, 0, 0);
            }
            __builtin_amdgcn_s_setprio(0);
            float g = 0.f;
            #pragma unroll
            for (int a = 0; a < 4; ++a)
                #pragma unroll
                for (int reg = 0; reg < 4; ++reg) {
                    float m = acc[a][reg];
                    rt1 = fmaf(m * m, uh[a][reg], rt1);
                    g   = fmaf(m, uu[a][reg], g);
                }
            g += __shfl_xor(g, 16, 64);
            g += __shfl_xor(g, 32, 64);
            if (lane < 16) gw[ww][wave][kt * 16 + lane] = g;
        }

        rt1 += __shfl_xor(rt1, 16, 64);
        rt1 += __shfl_xor(rt1, 32, 64);
        if (lane < 16) rt1p[ww][wave][lane] = rt1;

        __syncthreads();   // all reads of AsT done; gw/rt1p[ww] durable

        if (more) {
            #pragma unroll
            for (int s2 = 0; s2 < 6; ++s2) {
                int k = s2 * 8 + k0;
                *(half8*)(AsT + k * HID + ((ci ^ (k & 7)) * 8)) = w1r[s2] * th;
            }
        }
        __syncthreads();   // AsT next walker ready
    }

    // ---- deferred final combine: wave handles walkers 2*wave, 2*wave+1 ----
    const int wa = 2 * wave, wb = wa + 1;
    float rt2a = rt2s[wa];
    float rt2b = rt2s[wb];

    float r0 = rt1p[wa][quad][n16];
    float r1 = rt1p[wb][quad][n16];

    float ga = 0.f, gb = 0.f, xa = 0.f, xb = 0.f;
    if (lane < NXD) {
        ga = gw[wa][0][lane] + gw[wa][1][lane] + gw[wa][2][lane] + gw[wa][3][lane];
        gb = gw[wb][0][lane] + gw[wb][1][lane] + gw[wb][2][lane] + gw[wb][3][lane];
        xa = xs[wa][lane];
        xb = xs[wb][lane];
    }
    float gga = ga * ga, ggb = gb * gb;
    float pa = 0.5f * xa * xa, pb = 0.5f * xb * xb;
    #pragma unroll
    for (int off = 32; off > 0; off >>= 1) {
        r0  += __shfl_down(r0,  off, 64);
        r1  += __shfl_down(r1,  off, 64);
        gga += __shfl_down(gga, off, 64);
        ggb += __shfl_down(ggb, off, 64);
        pa  += __shfl_down(pa,  off, 64);
        pb  += __shfl_down(pb,  off, 64);
    }
    if (lane == 0) {
        float kina = r0 + rt2a - 0.5f * gga;
        float kinb = r1 + rt2b - 0.5f * ggb;

        float x0 = xs[wa][0], x1 = xs[wa][1], x2 = xs[wa][2];
        float x3 = xs[wa][3], x4 = xs[wa][4], x5 = xs[wa][5];
        float d01 = (x0-x1)*(x0-x1) + (x2-x1)*(x2-x1);
        float d02 = (x0-x2)*(x0-x2) + (x1-x2)*(x1-x2);
        float d12 = (x3-x5)*(x3-x5) + (x4-x5)*(x4-x5);
        float intera = GCONST * (expf(-2.f*d01) + expf(-2.f*d02) + expf(-2.f*d12));

        x0 = xs[wb][0]; x1 = xs[wb][1]; x2 = xs[wb][2];
        x3 = xs[wb][3]; x4 = xs[wb][4]; x5 = xs[wb][5];
        float e01 = (x0-x1)*(x0-x1) + (x2-x1)*(x2-x1);
        float e02 = (x0-x2)*(x0-x2) + (x1-x2)*(x1-x2);
        float e12 = (x3-x5)*(x3-x5) + (x4-x5)*(x4-x5);
        float interb = GCONST * (expf(-2.f*e01) + expf(-2.f*e02) + expf(-2.f*e12));

        const int wga = w0 + wa, wgb = w0 + wb;
        out[wga]             = kina + pa + intera;
        out[NWALK + wga]     = kina;
        out[2 * NWALK + wga] = pa;
        out[3 * NWALK + wga] = intera;
        out[wgb]             = kinb + pb + interb;
        out[NWALK + wgb]     = kinb;
        out[2 * NWALK + wgb] = pb;
        out[3 * NWALK + wgb] = interb;
    }
}

extern "C" void kernel_launch(void* const* d_in, const int* in_sizes, int n_in,
                              void* d_out, int out_size, void* d_ws, size_t ws_size,
                              hipStream_t stream) {
    const float* x  = (const float*)d_in[0];
    const float* W1 = (const float*)d_in[1];
    const float* b1 = (const float*)d_in[2];
    const float* W2 = (const float*)d_in[3];
    const float* b2 = (const float*)d_in[4];
    const float* w3 = (const float*)d_in[5];
    float* out = (float*)d_out;

    char* ws = (char*)d_ws;
    _Float16* W2c = (_Float16*)(ws);                       // 128 KB
    _Float16* W1c = (_Float16*)(ws + 131072);              // 24 KB
    _Float16* t1h = (_Float16*)(ws + 155648);              // 2 MB
    _Float16* h1h = (_Float16*)(ws + 2252800);             // 2 MB
    _Float16* chv = (_Float16*)(ws + 4349952);             // 2 MB

    prep_all<<<16 + NWALK / 16, 256, 0, stream>>>(W2, W1, x, b1, W2c, W1c, t1h, h1h, chv);
    eloc8<<<NWALK / WPB, 256, 0, stream>>>(x, b2, w3, W2c, W1c, t1h, h1h, chv, out);
}